// Round 16
// baseline (1007.153 us; speedup 1.0000x reference)
//
#include <hip/hip_runtime.h>
#include <stdint.h>

// ---------------- problem constants ----------------
#define T_STEPS 2048
#define BATCH   32
#define NIN     512
#define NOUT    256
#define MROWS   (T_STEPS*BATCH)   // 65536
#define BO      (BATCH*NOUT)      // 8192
#define NCHUNK  32
#define CHLEN   (T_STEPS/NCHUNK)  // 64

typedef _Float16 f16x8 __attribute__((ext_vector_type(8)));
typedef _Float16 f16x4 __attribute__((ext_vector_type(4)));
typedef float    fx4   __attribute__((ext_vector_type(4)));

#define LDSP(p) ((__attribute__((address_space(3))) void*)(p))
#define GLBP(p) ((const __attribute__((address_space(1))) void*)(p))

#define BAR()        asm volatile("s_barrier" ::: "memory")
#define WAITLGKM0()  do { asm volatile("s_waitcnt lgkmcnt(0)" ::: "memory"); __builtin_amdgcn_sched_barrier(0); } while(0)
#define WAITVM(n)    do { asm volatile("s_waitcnt vmcnt(" #n ")" ::: "memory"); __builtin_amdgcn_sched_barrier(0); } while(0)

// ---------------- weights: 4x [256,512] f32 -> Wcat [1024][512] f16 -------
__global__ __launch_bounds__(256) void convert_w(
    const float* __restrict__ Wx, const float* __restrict__ Wf,
    const float* __restrict__ Wr, const float* __restrict__ Wc,
    _Float16* __restrict__ Wcat)
{
    int idx = blockIdx.x * 256 + threadIdx.x;
    int n  = idx >> 7;
    int k4 = (idx & 127) * 4;
    int g = n >> 8, o = n & 255;
    const float* W = (g == 0) ? Wx : (g == 1) ? Wf : (g == 2) ? Wr : Wc;
    float4 v = *(const float4*)(W + o * NIN + k4);
    f16x4 h;
    h[0] = (_Float16)v.x; h[1] = (_Float16)v.y;
    h[2] = (_Float16)v.z; h[3] = (_Float16)v.w;
    *(f16x4*)(Wcat + n * NIN + k4) = h;
}

// ---------------- persistent 256x256 GEMM: A fused via LDS, B direct-L2 ---
// B (Wcat, 1 MB) is L2-resident: fragments are read straight from global
// (16 rows x 64 B contiguous per instr — full cache lines), deleting all
// B LDS staging.  LDS = A only (64 KiB) -> with VGPR<=128 two blocks/CU
// co-reside, overlapping one block's LDS phase with the other's MFMA.
// A keeps the R12/R13 full-tile-cover recipe: ph4 WAITVM(0) -> AWRITE(g+1)
// (reg set dead) -> ALOAD(g+2) same set.  B-frag waits (compiler-inserted
// vmcnt) partially drain A(g+1) early — bounded cost, 3/4 of A reads are
// co-XCD L2 hits.
#define BM 256
#define BN 256
#define BK 64
#define NGT 32            // 4 m-tiles x 8 k-tiles

__global__ __launch_bounds__(512, 4) void gemm_proj(
    const float*    __restrict__ xt,      // [MROWS][512] f32
    const _Float16* __restrict__ Wcat,    // [1024][512]  f16
    const float* __restrict__ bfv, const float* __restrict__ brv, const float* __restrict__ bcv,
    _Float16* __restrict__ xp_h, _Float16* __restrict__ f_h,
    _Float16* __restrict__ r_h,  _Float16* __restrict__ cx_h)
{
    __shared__ char lds[65536];   // A only: [parity][half][128 rows][128B]

    const int tid  = threadIdx.x;
    const int lane = tid & 63;
    const int w    = tid >> 6;       // 0..7
    const int wrq  = w >> 2;         // 0..1
    const int wcq  = w & 3;          // 0..3
    const int lr = lane & 15, lk = lane >> 4;

    // XCD-chunked bijective swizzle: 256 wgs, 32/XCD; the 4 cg-blocks of one
    // mgrp are co-XCD (A f32 panel read 4x -> 3 of 4 served by that XCD L2).
    int wg = (blockIdx.x & 7) * 32 + (blockIdx.x >> 3);
    const int  cg   = wg & 3;        // output group 0..3
    const int  mgrp = wg >> 2;       // 0..63
    const long m0 = (long)mgrp * 1024;   // 4 m-tiles of 256 rows
    const int  n0 = cg * BN;

    // ---- A staging maps (reg-staged f32, coalesced 16B/lane) ----
    const char* baseAg = (const char*)xt + (m0 + (tid >> 4)) * 2048 + (tid & 15) * 16;
    const int awbase = (tid >> 4) * 128 + (((tid & 15) * 8) ^ (((tid >> 4) & 7) << 4));

    // ---- B fragment global base: row n0 + wcq*32 + lr, k-slot lk*16 B ----
    const char* baseBG = (const char*)Wcat
        + ((long)(n0 + wcq * 32 + lr)) * 1024 + lk * 16;

    // single A reg set (static indexing only — rule 20)
    float4 av_h0[4], av_h1[4];
#define ALOAD_H(gi, half, dst) do {                                          \
        const char* _b = baseAg + (long)((gi) >> 3) * 524288                 \
                         + ((gi) & 7) * 256 + (half) * 262144;               \
        _Pragma("unroll")                                                    \
        for (int jj = 0; jj < 4; ++jj)                                       \
            dst[jj] = *(const float4*)(_b + jj * 65536);                     \
    } while (0)
#define AWRITE_H(gi, half, src) do {                                         \
        char* _d = lds + ((gi) & 1) * 32768 + (half) * 16384 + awbase;       \
        _Pragma("unroll")                                                    \
        for (int jj = 0; jj < 4; ++jj) {                                     \
            f16x4 _h;                                                        \
            _h[0] = (_Float16)src[jj].x; _h[1] = (_Float16)src[jj].y;        \
            _h[2] = (_Float16)src[jj].z; _h[3] = (_Float16)src[jj].w;        \
            *(f16x4*)(_d + jj * 4096) = _h;                                  \
        }                                                                    \
    } while (0)

    fx4 acc[2][2][4][2];
    #pragma unroll
    for (int a = 0; a < 2; ++a)
        #pragma unroll
        for (int b = 0; b < 2; ++b)
            #pragma unroll
            for (int c = 0; c < 4; ++c)
                #pragma unroll
                for (int d = 0; d < 2; ++d)
                    acc[a][b][c][d] = (fx4){0.f, 0.f, 0.f, 0.f};

    f16x8 Ar[4][2];    // current A-half fragments [mf][kk]
    f16x8 B0r[2][2];   // B-half0 fragments [nf][kk]
    f16x8 B1r[2][2];   // B-half1 fragments

#define READ_A(c2, h) do {                                                   \
        _Pragma("unroll")                                                    \
        for (int mf = 0; mf < 4; ++mf) {                                     \
            int rl = wrq * 64 + mf * 16 + lr;                                \
            int rb = (c2) * 32768 + (h) * 16384 + rl * 128;                  \
            _Pragma("unroll")                                                \
            for (int kk = 0; kk < 2; ++kk)                                   \
                Ar[mf][kk] = *(const f16x8*)(lds + rb +                      \
                    ((kk * 64 + lk * 16) ^ ((rl & 7) << 4)));                \
        }                                                                    \
    } while (0)
    // B frags direct from global (bit-identical to the old LDS-path values):
    // global row = n0 + h*128 + wcq*32 + nf*16 + lr ; k-byte = kt*128+kk*64+lk*16
#define READ_BG(g, h, dst) do {                                              \
        _Pragma("unroll")                                                    \
        for (int nf = 0; nf < 2; ++nf)                                       \
            _Pragma("unroll")                                                \
            for (int kk = 0; kk < 2; ++kk)                                   \
                dst[nf][kk] = *(const f16x8*)(baseBG + (h) * 131072          \
                    + nf * 16384 + ((g) & 7) * 128 + kk * 64);               \
    } while (0)
    // swapped operands: D[col=lane&15 -> m (A)], [reg j -> o (B)]
#define MMACC(Qr, Qc, Br) do {                                               \
        __builtin_amdgcn_s_setprio(1);                                       \
        _Pragma("unroll")                                                    \
        for (int kk = 0; kk < 2; ++kk)                                       \
            _Pragma("unroll")                                                \
            for (int mf = 0; mf < 4; ++mf)                                   \
                _Pragma("unroll")                                            \
                for (int nf = 0; nf < 2; ++nf)                               \
                    acc[Qr][Qc][mf][nf] = __builtin_amdgcn_mfma_f32_16x16x32_f16( \
                        Br[nf][kk], Ar[mf][kk], acc[Qr][Qc][mf][nf], 0, 0, 0);    \
        __builtin_amdgcn_s_setprio(0);                                       \
    } while (0)

    const int g_out = cg;
    _Float16* outp = (g_out == 0) ? xp_h : (g_out == 1) ? f_h : (g_out == 2) ? r_h : cx_h;
    const float* bias = (g_out == 1) ? bfv : (g_out == 2) ? brv : (g_out == 3) ? bcv : nullptr;

    // ---- prologue: A(0)->LDS; A(1) left in flight ----
    ALOAD_H(0, 0, av_h0); ALOAD_H(0, 1, av_h1);    // 8 vm
    WAITVM(0);                                     // A(0) landed
    AWRITE_H(0, 0, av_h0); AWRITE_H(0, 1, av_h1);
    ALOAD_H(1, 0, av_h0); ALOAD_H(1, 1, av_h1);    // 8 in flight
    WAITLGKM0();                                   // A writes visible
    BAR();

    for (int g = 0; g < NGT; ++g) {
        const int c2 = g & 1;
        // ---- h0 A frags + ALL B frags (compiler inserts vmcnt waits) ----
        READ_A(c2, 0);
        READ_BG(g, 0, B0r);
        READ_BG(g, 1, B1r);
        WAITLGKM0();
        MMACC(0, 0, B0r);
        MMACC(0, 1, B1r);
        // ---- h1 A frags ----
        READ_A(c2, 1);
        WAITLGKM0();
        MMACC(1, 0, B0r);
        MMACC(1, 1, B1r);
        // ---- A publish (full-tile-old) + next-next A issue ----
        WAITVM(0);
        if (g + 1 < NGT) {
            AWRITE_H(g + 1, 0, av_h0);   // set now dead ->
            AWRITE_H(g + 1, 1, av_h1);
            if (g + 2 < NGT) {           // reload immediately
                ALOAD_H(g + 2, 0, av_h0);
                ALOAD_H(g + 2, 1, av_h1);
            }
        }
        WAITLGKM0();                     // A ds_writes + reads complete
        BAR();                           // single tile-boundary barrier
        // ---- per-m-tile epilogue (g = mt*8+7): packed f16x4 stores ----
        if ((g & 7) == 7) {
            const long mbase = m0 + (long)(g >> 3) * 256;
            #pragma unroll
            for (int Qr = 0; Qr < 2; ++Qr) {
                #pragma unroll
                for (int Qc = 0; Qc < 2; ++Qc) {
                    #pragma unroll
                    for (int nf = 0; nf < 2; ++nf) {
                        const int ob = Qc * 128 + wcq * 32 + nf * 16 + lk * 4;
                        float4 bv4 = (g_out == 0) ? (float4){0.f, 0.f, 0.f, 0.f}
                                                  : *(const float4*)(bias + ob);
                        #pragma unroll
                        for (int mf = 0; mf < 4; ++mf) {
                            long row = mbase + Qr * 128 + wrq * 64 + mf * 16 + lr;
                            fx4 v = acc[Qr][Qc][mf][nf];
                            f16x4 hv;
                            if (g_out == 1 || g_out == 2) {
                                float p0 = v[0] + bv4.x, p1 = v[1] + bv4.y;
                                float p2 = v[2] + bv4.z, p3 = v[3] + bv4.w;
                                hv[0] = (_Float16)(__builtin_amdgcn_rcpf(1.0f + __expf(-p0)));
                                hv[1] = (_Float16)(__builtin_amdgcn_rcpf(1.0f + __expf(-p1)));
                                hv[2] = (_Float16)(__builtin_amdgcn_rcpf(1.0f + __expf(-p2)));
                                hv[3] = (_Float16)(__builtin_amdgcn_rcpf(1.0f + __expf(-p3)));
                            } else {
                                hv[0] = (_Float16)(v[0] + bv4.x);
                                hv[1] = (_Float16)(v[1] + bv4.y);
                                hv[2] = (_Float16)(v[2] + bv4.z);
                                hv[3] = (_Float16)(v[3] + bv4.w);
                            }
                            *(f16x4*)(outp + row * NOUT + ob) = hv;
                            acc[Qr][Qc][mf][nf] = (fx4){0.f, 0.f, 0.f, 0.f};
                        }
                    }
                }
            }
        }
    }
}

// ---------------- pass 2a: per-chunk affine composition (f16x4 loads) -----
__global__ __launch_bounds__(256) void chunk_scan_a(
    const _Float16* __restrict__ f_h, const _Float16* __restrict__ xp_h,
    float* __restrict__ chunkA, float* __restrict__ chunkB)
{
    int tid2 = blockIdx.x * 256 + threadIdx.x;   // 65536 threads
    int ch = tid2 >> 11;
    int b4 = (tid2 & 2047) << 2;                 // 4 consecutive bo lanes
    long base = (long)ch * CHLEN * BO + b4;
    fx4 a = (fx4){1.f, 1.f, 1.f, 1.f};
    fx4 cc = (fx4){0.f, 0.f, 0.f, 0.f};
    for (int s = 0; s < CHLEN; ++s) {
        long i = base + (long)s * BO;
        f16x4 fv = *(const f16x4*)(f_h + i);
        f16x4 xv = *(const f16x4*)(xp_h + i);
        #pragma unroll
        for (int q = 0; q < 4; ++q) {
            float f = (float)fv[q], x = (float)xv[q];
            cc[q] = f * cc[q] + (1.f - f) * x;
            a[q] *= f;
        }
    }
    *(fx4*)(chunkA + ch * BO + b4) = a;
    *(fx4*)(chunkB + ch * BO + b4) = cc;
}

// ---------------- pass 2b: propagate chunk states ----
__global__ __launch_bounds__(256) void chunk_prop(
    const float* __restrict__ ct0,
    const float* __restrict__ chunkA, const float* __restrict__ chunkB,
    float* __restrict__ cin, float* __restrict__ c_final)
{
    int bo = blockIdx.x * 256 + threadIdx.x;   // 8192
    float c = ct0[bo];
    #pragma unroll
    for (int ch = 0; ch < NCHUNK; ++ch) {
        cin[ch * BO + bo] = c;
        c = chunkA[ch * BO + bo] * c + chunkB[ch * BO + bo];
    }
    c_final[bo] = c;
}

// ---------------- pass 2c: final scan producing ht (f16x4/float4) --------
__global__ __launch_bounds__(256) void chunk_scan_h(
    const _Float16* __restrict__ xp_h, const _Float16* __restrict__ f_h,
    const _Float16* __restrict__ r_h,  const _Float16* __restrict__ cx_h,
    const float* __restrict__ cin, float* __restrict__ ht)
{
    int tid2 = blockIdx.x * 256 + threadIdx.x;   // 65536 threads
    int ch = tid2 >> 11;
    int b4 = (tid2 & 2047) << 2;
    long base = (long)ch * CHLEN * BO + b4;
    fx4 c = *(const fx4*)(cin + ch * BO + b4);
    for (int s = 0; s < CHLEN; ++s) {
        long i = base + (long)s * BO;
        f16x4 fv  = *(const f16x4*)(f_h + i);
        f16x4 xv  = *(const f16x4*)(xp_h + i);
        f16x4 rv  = *(const f16x4*)(r_h + i);
        f16x4 cxv = *(const f16x4*)(cx_h + i);
        fx4 h4;
        #pragma unroll
        for (int q = 0; q < 4; ++q) {
            float f = (float)fv[q], x = (float)xv[q];
            float r = (float)rv[q], cx = (float)cxv[q];
            c[q] = f * c[q] + (1.f - f) * x;
            float e = __expf(2.f * c[q]);                  // tanh=(e-1)/(e+1)
            float th = (e - 1.f) * __builtin_amdgcn_rcpf(e + 1.f);
            h4[q] = r * th + (1.f - r) * cx;
        }
        *(fx4*)(ht + i) = h4;
    }
}

// ---------------- launcher ----------------
extern "C" void kernel_launch(void* const* d_in, const int* in_sizes, int n_in,
                              void* d_out, int out_size, void* d_ws, size_t ws_size,
                              hipStream_t stream) {
    const float* xt  = (const float*)d_in[0];
    const float* ct0 = (const float*)d_in[1];
    const float* Wx  = (const float*)d_in[2];
    const float* Wf  = (const float*)d_in[3];
    const float* bf_ = (const float*)d_in[4];
    const float* Wr  = (const float*)d_in[5];
    const float* br_ = (const float*)d_in[6];
    const float* Wc  = (const float*)d_in[7];
    const float* bc_ = (const float*)d_in[8];

    float* ht      = (float*)d_out;
    float* c_final = ht + (size_t)MROWS * NOUT;

    char* ws = (char*)d_ws;
    _Float16* Wcat = (_Float16*)ws;                          // 1 MiB
    _Float16* xp_h = (_Float16*)(ws + (1 << 20));            // 32 MiB each
    _Float16* f_h  = xp_h + (size_t)MROWS * NOUT;
    _Float16* r_h  = f_h  + (size_t)MROWS * NOUT;
    _Float16* cx_h = r_h  + (size_t)MROWS * NOUT;
    float* chunkA  = (float*)(cx_h + (size_t)MROWS * NOUT);  // 1 MiB
    float* chunkB  = chunkA + NCHUNK * BO;
    float* cin     = chunkB + NCHUNK * BO;
    // total ws use ~ 132 MiB

    convert_w<<<512, 256, 0, stream>>>(Wx, Wf, Wr, Wc, Wcat);
    gemm_proj<<<256, 512, 0, stream>>>(
        xt, Wcat, bf_, br_, bc_, xp_h, f_h, r_h, cx_h);
    chunk_scan_a<<<256, 256, 0, stream>>>(f_h, xp_h, chunkA, chunkB);
    chunk_prop<<<BO / 256, 256, 0, stream>>>(ct0, chunkA, chunkB, cin, c_final);
    chunk_scan_h<<<256, 256, 0, stream>>>(xp_h, f_h, r_h, cx_h, cin, ht);
}

// Round 17
// 196.380 us; speedup vs baseline: 5.1286x; 5.1286x over previous
//
#include <hip/hip_runtime.h>
#include <stdint.h>

// ---------------- problem constants ----------------
#define T_STEPS 2048
#define BATCH   32
#define NIN     512
#define NOUT    256
#define MROWS   (T_STEPS*BATCH)   // 65536
#define BO      (BATCH*NOUT)      // 8192
#define NCHUNK  32
#define CHLEN   (T_STEPS/NCHUNK)  // 64

typedef _Float16 f16x8 __attribute__((ext_vector_type(8)));
typedef _Float16 f16x4 __attribute__((ext_vector_type(4)));
typedef float    fx4   __attribute__((ext_vector_type(4)));

#define LDSP(p) ((__attribute__((address_space(3))) void*)(p))
#define GLBP(p) ((const __attribute__((address_space(1))) void*)(p))

#define BAR()        asm volatile("s_barrier" ::: "memory")
#define WAITLGKM0()  do { asm volatile("s_waitcnt lgkmcnt(0)" ::: "memory"); __builtin_amdgcn_sched_barrier(0); } while(0)
#define WAITVM(n)    do { asm volatile("s_waitcnt vmcnt(" #n ")" ::: "memory"); __builtin_amdgcn_sched_barrier(0); } while(0)

// ---------------- weights: 4x [256,512] f32 -> Wcat [1024][512] f16 -------
__global__ __launch_bounds__(256) void convert_w(
    const float* __restrict__ Wx, const float* __restrict__ Wf,
    const float* __restrict__ Wr, const float* __restrict__ Wc,
    _Float16* __restrict__ Wcat)
{
    int idx = blockIdx.x * 256 + threadIdx.x;
    int n  = idx >> 7;
    int k4 = (idx & 127) * 4;
    int g = n >> 8, o = n & 255;
    const float* W = (g == 0) ? Wx : (g == 1) ? Wf : (g == 2) ? Wr : Wc;
    float4 v = *(const float4*)(W + o * NIN + k4);
    f16x4 h;
    h[0] = (_Float16)v.x; h[1] = (_Float16)v.y;
    h[2] = (_Float16)v.z; h[3] = (_Float16)v.w;
    *(f16x4*)(Wcat + n * NIN + k4) = h;
}

// ---------------- 256x256 GEMM: A fused via LDS, B direct from L2 ---------
// R15 design with both launch bugs fixed: natural VGPR (<=128, (512,1))
// and GRID 512 (2 m-tiles/block) so TWO 8-wave blocks co-reside per CU
// (LDS 64 KiB x2, VGPR 128 = 4 waves/SIMD cap) -> one block's staging
// overlaps the other's MFMA (m114).  B (Wcat, 1 MB, L2-resident) fragments
// are read straight from global: 16 rows x 64 B contiguous per instr.
// A keeps the R12/R13 full-tile-cover recipe: end-of-tile WAITVM(0) ->
// AWRITE(g+1) (reg set dead) -> ALOAD(g+2) same set.
#define BM 256
#define BN 256
#define BK 64
#define NGT 16            // 2 m-tiles x 8 k-tiles

__global__ __launch_bounds__(512, 1) void gemm_proj(
    const float*    __restrict__ xt,      // [MROWS][512] f32
    const _Float16* __restrict__ Wcat,    // [1024][512]  f16
    const float* __restrict__ bfv, const float* __restrict__ brv, const float* __restrict__ bcv,
    _Float16* __restrict__ xp_h, _Float16* __restrict__ f_h,
    _Float16* __restrict__ r_h,  _Float16* __restrict__ cx_h)
{
    __shared__ char lds[65536];   // A only: [parity][half][128 rows][128B]

    const int tid  = threadIdx.x;
    const int lane = tid & 63;
    const int w    = tid >> 6;       // 0..7
    const int wrq  = w >> 2;         // 0..1
    const int wcq  = w & 3;          // 0..3
    const int lr = lane & 15, lk = lane >> 4;

    // XCD-chunked bijective swizzle: 512 wgs, 64/XCD; the 4 cg-blocks of one
    // mgrp are co-XCD (A f32 panel read 4x -> 3 of 4 served by that XCD L2).
    int wg = (blockIdx.x & 7) * 64 + (blockIdx.x >> 3);
    const int  cg   = wg & 3;        // output group 0..3
    const int  mgrp = wg >> 2;       // 0..127
    const long m0 = (long)mgrp * 512;    // 2 m-tiles of 256 rows
    const int  n0 = cg * BN;

    // ---- A staging maps (reg-staged f32, coalesced 16B/lane) ----
    const char* baseAg = (const char*)xt + (m0 + (tid >> 4)) * 2048 + (tid & 15) * 16;
    const int awbase = (tid >> 4) * 128 + (((tid & 15) * 8) ^ (((tid >> 4) & 7) << 4));

    // ---- B fragment global base: row n0 + wcq*32 + lr, k-slot lk*16 B ----
    const char* baseBG = (const char*)Wcat
        + ((long)(n0 + wcq * 32 + lr)) * 1024 + lk * 16;

    // single A reg set (static indexing only — rule 20)
    float4 av_h0[4], av_h1[4];
#define ALOAD_H(gi, half, dst) do {                                          \
        const char* _b = baseAg + (long)((gi) >> 3) * 524288                 \
                         + ((gi) & 7) * 256 + (half) * 262144;               \
        _Pragma("unroll")                                                    \
        for (int jj = 0; jj < 4; ++jj)                                       \
            dst[jj] = *(const float4*)(_b + jj * 65536);                     \
    } while (0)
#define AWRITE_H(gi, half, src) do {                                         \
        char* _d = lds + ((gi) & 1) * 32768 + (half) * 16384 + awbase;       \
        _Pragma("unroll")                                                    \
        for (int jj = 0; jj < 4; ++jj) {                                     \
            f16x4 _h;                                                        \
            _h[0] = (_Float16)src[jj].x; _h[1] = (_Float16)src[jj].y;        \
            _h[2] = (_Float16)src[jj].z; _h[3] = (_Float16)src[jj].w;        \
            *(f16x4*)(_d + jj * 4096) = _h;                                  \
        }                                                                    \
    } while (0)

    fx4 acc[2][2][4][2];
    #pragma unroll
    for (int a = 0; a < 2; ++a)
        #pragma unroll
        for (int b = 0; b < 2; ++b)
            #pragma unroll
            for (int c = 0; c < 4; ++c)
                #pragma unroll
                for (int d = 0; d < 2; ++d)
                    acc[a][b][c][d] = (fx4){0.f, 0.f, 0.f, 0.f};

    f16x8 Ar[4][2];    // current A-half fragments [mf][kk]
    f16x8 B0r[2][2];   // B-half0 fragments [nf][kk]
    f16x8 B1r[2][2];   // B-half1 fragments

#define READ_A(c2, h) do {                                                   \
        _Pragma("unroll")                                                    \
        for (int mf = 0; mf < 4; ++mf) {                                     \
            int rl = wrq * 64 + mf * 16 + lr;                                \
            int rb = (c2) * 32768 + (h) * 16384 + rl * 128;                  \
            _Pragma("unroll")                                                \
            for (int kk = 0; kk < 2; ++kk)                                   \
                Ar[mf][kk] = *(const f16x8*)(lds + rb +                      \
                    ((kk * 64 + lk * 16) ^ ((rl & 7) << 4)));                \
        }                                                                    \
    } while (0)
    // B frags direct from global (bit-identical to the old LDS-path values):
    // global row = n0 + h*128 + wcq*32 + nf*16 + lr ; k-byte = kt*128+kk*64+lk*16
#define READ_BG(g, h, dst) do {                                              \
        _Pragma("unroll")                                                    \
        for (int nf = 0; nf < 2; ++nf)                                       \
            _Pragma("unroll")                                                \
            for (int kk = 0; kk < 2; ++kk)                                   \
                dst[nf][kk] = *(const f16x8*)(baseBG + (h) * 131072          \
                    + nf * 16384 + ((g) & 7) * 128 + kk * 64);               \
    } while (0)
    // swapped operands: D[col=lane&15 -> m (A)], [reg j -> o (B)]
#define MMACC(Qr, Qc, Br) do {                                               \
        __builtin_amdgcn_s_setprio(1);                                       \
        _Pragma("unroll")                                                    \
        for (int kk = 0; kk < 2; ++kk)                                       \
            _Pragma("unroll")                                                \
            for (int mf = 0; mf < 4; ++mf)                                   \
                _Pragma("unroll")                                            \
                for (int nf = 0; nf < 2; ++nf)                               \
                    acc[Qr][Qc][mf][nf] = __builtin_amdgcn_mfma_f32_16x16x32_f16( \
                        Br[nf][kk], Ar[mf][kk], acc[Qr][Qc][mf][nf], 0, 0, 0);    \
        __builtin_amdgcn_s_setprio(0);                                       \
    } while (0)

    const int g_out = cg;
    _Float16* outp = (g_out == 0) ? xp_h : (g_out == 1) ? f_h : (g_out == 2) ? r_h : cx_h;
    const float* bias = (g_out == 1) ? bfv : (g_out == 2) ? brv : (g_out == 3) ? bcv : nullptr;

    // ---- prologue: A(0)->LDS; A(1) left in flight ----
    ALOAD_H(0, 0, av_h0); ALOAD_H(0, 1, av_h1);    // 8 vm
    WAITVM(0);                                     // A(0) landed
    AWRITE_H(0, 0, av_h0); AWRITE_H(0, 1, av_h1);
    ALOAD_H(1, 0, av_h0); ALOAD_H(1, 1, av_h1);    // 8 in flight
    WAITLGKM0();                                   // A writes visible
    BAR();

    for (int g = 0; g < NGT; ++g) {
        const int c2 = g & 1;
        // ---- h0 A frags + ALL B frags (compiler inserts vmcnt waits) ----
        READ_A(c2, 0);
        READ_BG(g, 0, B0r);
        READ_BG(g, 1, B1r);
        WAITLGKM0();
        MMACC(0, 0, B0r);
        MMACC(0, 1, B1r);
        // ---- h1 A frags ----
        READ_A(c2, 1);
        WAITLGKM0();
        MMACC(1, 0, B0r);
        MMACC(1, 1, B1r);
        // ---- A publish (full-tile-old) + next-next A issue ----
        WAITVM(0);
        if (g + 1 < NGT) {
            AWRITE_H(g + 1, 0, av_h0);   // set now dead ->
            AWRITE_H(g + 1, 1, av_h1);
            if (g + 2 < NGT) {           // reload immediately
                ALOAD_H(g + 2, 0, av_h0);
                ALOAD_H(g + 2, 1, av_h1);
            }
        }
        WAITLGKM0();                     // A ds_writes + reads complete
        BAR();                           // single tile-boundary barrier
        // ---- per-m-tile epilogue (g = mt*8+7): packed f16x4 stores ----
        if ((g & 7) == 7) {
            const long mbase = m0 + (long)(g >> 3) * 256;
            #pragma unroll
            for (int Qr = 0; Qr < 2; ++Qr) {
                #pragma unroll
                for (int Qc = 0; Qc < 2; ++Qc) {
                    #pragma unroll
                    for (int nf = 0; nf < 2; ++nf) {
                        const int ob = Qc * 128 + wcq * 32 + nf * 16 + lk * 4;
                        float4 bv4 = (g_out == 0) ? (float4){0.f, 0.f, 0.f, 0.f}
                                                  : *(const float4*)(bias + ob);
                        #pragma unroll
                        for (int mf = 0; mf < 4; ++mf) {
                            long row = mbase + Qr * 128 + wrq * 64 + mf * 16 + lr;
                            fx4 v = acc[Qr][Qc][mf][nf];
                            f16x4 hv;
                            if (g_out == 1 || g_out == 2) {
                                float p0 = v[0] + bv4.x, p1 = v[1] + bv4.y;
                                float p2 = v[2] + bv4.z, p3 = v[3] + bv4.w;
                                hv[0] = (_Float16)(__builtin_amdgcn_rcpf(1.0f + __expf(-p0)));
                                hv[1] = (_Float16)(__builtin_amdgcn_rcpf(1.0f + __expf(-p1)));
                                hv[2] = (_Float16)(__builtin_amdgcn_rcpf(1.0f + __expf(-p2)));
                                hv[3] = (_Float16)(__builtin_amdgcn_rcpf(1.0f + __expf(-p3)));
                            } else {
                                hv[0] = (_Float16)(v[0] + bv4.x);
                                hv[1] = (_Float16)(v[1] + bv4.y);
                                hv[2] = (_Float16)(v[2] + bv4.z);
                                hv[3] = (_Float16)(v[3] + bv4.w);
                            }
                            *(f16x4*)(outp + row * NOUT + ob) = hv;
                            acc[Qr][Qc][mf][nf] = (fx4){0.f, 0.f, 0.f, 0.f};
                        }
                    }
                }
            }
        }
    }
}

// ---------------- pass 2a: per-chunk affine composition (f16x4 loads) -----
__global__ __launch_bounds__(256) void chunk_scan_a(
    const _Float16* __restrict__ f_h, const _Float16* __restrict__ xp_h,
    float* __restrict__ chunkA, float* __restrict__ chunkB)
{
    int tid2 = blockIdx.x * 256 + threadIdx.x;   // 65536 threads
    int ch = tid2 >> 11;
    int b4 = (tid2 & 2047) << 2;                 // 4 consecutive bo lanes
    long base = (long)ch * CHLEN * BO + b4;
    fx4 a = (fx4){1.f, 1.f, 1.f, 1.f};
    fx4 cc = (fx4){0.f, 0.f, 0.f, 0.f};
    for (int s = 0; s < CHLEN; ++s) {
        long i = base + (long)s * BO;
        f16x4 fv = *(const f16x4*)(f_h + i);
        f16x4 xv = *(const f16x4*)(xp_h + i);
        #pragma unroll
        for (int q = 0; q < 4; ++q) {
            float f = (float)fv[q], x = (float)xv[q];
            cc[q] = f * cc[q] + (1.f - f) * x;
            a[q] *= f;
        }
    }
    *(fx4*)(chunkA + ch * BO + b4) = a;
    *(fx4*)(chunkB + ch * BO + b4) = cc;
}

// ---------------- pass 2b: propagate chunk states ----
__global__ __launch_bounds__(256) void chunk_prop(
    const float* __restrict__ ct0,
    const float* __restrict__ chunkA, const float* __restrict__ chunkB,
    float* __restrict__ cin, float* __restrict__ c_final)
{
    int bo = blockIdx.x * 256 + threadIdx.x;   // 8192
    float c = ct0[bo];
    #pragma unroll
    for (int ch = 0; ch < NCHUNK; ++ch) {
        cin[ch * BO + bo] = c;
        c = chunkA[ch * BO + bo] * c + chunkB[ch * BO + bo];
    }
    c_final[bo] = c;
}

// ---------------- pass 2c: final scan producing ht (f16x4/float4) --------
__global__ __launch_bounds__(256) void chunk_scan_h(
    const _Float16* __restrict__ xp_h, const _Float16* __restrict__ f_h,
    const _Float16* __restrict__ r_h,  const _Float16* __restrict__ cx_h,
    const float* __restrict__ cin, float* __restrict__ ht)
{
    int tid2 = blockIdx.x * 256 + threadIdx.x;   // 65536 threads
    int ch = tid2 >> 11;
    int b4 = (tid2 & 2047) << 2;
    long base = (long)ch * CHLEN * BO + b4;
    fx4 c = *(const fx4*)(cin + ch * BO + b4);
    for (int s = 0; s < CHLEN; ++s) {
        long i = base + (long)s * BO;
        f16x4 fv  = *(const f16x4*)(f_h + i);
        f16x4 xv  = *(const f16x4*)(xp_h + i);
        f16x4 rv  = *(const f16x4*)(r_h + i);
        f16x4 cxv = *(const f16x4*)(cx_h + i);
        fx4 h4;
        #pragma unroll
        for (int q = 0; q < 4; ++q) {
            float f = (float)fv[q], x = (float)xv[q];
            float r = (float)rv[q], cx = (float)cxv[q];
            c[q] = f * c[q] + (1.f - f) * x;
            float e = __expf(2.f * c[q]);                  // tanh=(e-1)/(e+1)
            float th = (e - 1.f) * __builtin_amdgcn_rcpf(e + 1.f);
            h4[q] = r * th + (1.f - r) * cx;
        }
        *(fx4*)(ht + i) = h4;
    }
}

// ---------------- launcher ----------------
extern "C" void kernel_launch(void* const* d_in, const int* in_sizes, int n_in,
                              void* d_out, int out_size, void* d_ws, size_t ws_size,
                              hipStream_t stream) {
    const float* xt  = (const float*)d_in[0];
    const float* ct0 = (const float*)d_in[1];
    const float* Wx  = (const float*)d_in[2];
    const float* Wf  = (const float*)d_in[3];
    const float* bf_ = (const float*)d_in[4];
    const float* Wr  = (const float*)d_in[5];
    const float* br_ = (const float*)d_in[6];
    const float* Wc  = (const float*)d_in[7];
    const float* bc_ = (const float*)d_in[8];

    float* ht      = (float*)d_out;
    float* c_final = ht + (size_t)MROWS * NOUT;

    char* ws = (char*)d_ws;
    _Float16* Wcat = (_Float16*)ws;                          // 1 MiB
    _Float16* xp_h = (_Float16*)(ws + (1 << 20));            // 32 MiB each
    _Float16* f_h  = xp_h + (size_t)MROWS * NOUT;
    _Float16* r_h  = f_h  + (size_t)MROWS * NOUT;
    _Float16* cx_h = r_h  + (size_t)MROWS * NOUT;
    float* chunkA  = (float*)(cx_h + (size_t)MROWS * NOUT);  // 1 MiB
    float* chunkB  = chunkA + NCHUNK * BO;
    float* cin     = chunkB + NCHUNK * BO;
    // total ws use ~ 132 MiB

    convert_w<<<512, 256, 0, stream>>>(Wx, Wf, Wr, Wc, Wcat);
    gemm_proj<<<512, 512, 0, stream>>>(
        xt, Wcat, bf_, br_, bc_, xp_h, f_h, r_h, cx_h);
    chunk_scan_a<<<256, 256, 0, stream>>>(f_h, xp_h, chunkA, chunkB);
    chunk_prop<<<BO / 256, 256, 0, stream>>>(ct0, chunkA, chunkB, cin, c_final);
    chunk_scan_h<<<256, 256, 0, stream>>>(xp_h, f_h, r_h, cx_h, cin, ht);
}

// Round 18
// 174.608 us; speedup vs baseline: 5.7681x; 1.1247x over previous
//
#include <hip/hip_runtime.h>
#include <stdint.h>

// ---------------- problem constants ----------------
#define T_STEPS 2048
#define BATCH   32
#define NIN     512
#define NOUT    256
#define MROWS   (T_STEPS*BATCH)   // 65536
#define BO      (BATCH*NOUT)      // 8192
#define NCHUNK  32
#define CHLEN   (T_STEPS/NCHUNK)  // 64

typedef _Float16 f16x8 __attribute__((ext_vector_type(8)));
typedef _Float16 f16x4 __attribute__((ext_vector_type(4)));
typedef float    fx4   __attribute__((ext_vector_type(4)));

#define LDSP(p) ((__attribute__((address_space(3))) void*)(p))
#define GLBP(p) ((const __attribute__((address_space(1))) void*)(p))

#define BAR()        asm volatile("s_barrier" ::: "memory")
#define WAITLGKM0()  do { asm volatile("s_waitcnt lgkmcnt(0)" ::: "memory"); __builtin_amdgcn_sched_barrier(0); } while(0)
#define WAITVM(n)    do { asm volatile("s_waitcnt vmcnt(" #n ")" ::: "memory"); __builtin_amdgcn_sched_barrier(0); } while(0)

// ---------------- weights: 4x [256,512] f32 -> Wcat [1024][512] f16 -------
__global__ __launch_bounds__(256) void convert_w(
    const float* __restrict__ Wx, const float* __restrict__ Wf,
    const float* __restrict__ Wr, const float* __restrict__ Wc,
    _Float16* __restrict__ Wcat)
{
    int idx = blockIdx.x * 256 + threadIdx.x;
    int n  = idx >> 7;
    int k4 = (idx & 127) * 4;
    int g = n >> 8, o = n & 255;
    const float* W = (g == 0) ? Wx : (g == 1) ? Wf : (g == 2) ? Wr : Wc;
    float4 v = *(const float4*)(W + o * NIN + k4);
    f16x4 h;
    h[0] = (_Float16)v.x; h[1] = (_Float16)v.y;
    h[2] = (_Float16)v.z; h[3] = (_Float16)v.w;
    *(f16x4*)(Wcat + n * NIN + k4) = h;
}

// ---------------- persistent 256x256 GEMM, fused A, 1-barrier/K-step ------
// [SESSION CHAMPION — R13 structure, 176.05 us total, gemm ~126.5 us]
// EVERYTHING staged 1 tile ahead into the opposite LDS parity -> no mid
// barrier.  Per tile g: ph1 STAGE_B(g+1,0); ph2 STAGE_B(g+1,1); ph4
// WAITVM(0) (A(g+1) is a full tile old, B(g+1,*) >= 2 phases & L2-hot) ->
// AWRITE A(g+1) -> ALOAD A(g+2) (same reg set, dead after AWRITE) ->
// lgkm -> BAR.  FIFO: enter with A(g+1)x8; +B(g+1,0)2 +B(g+1,1)2 = 12;
// drain; reload 8.  Prologue enters g=0 with exactly A(1)x8.
// Measured structural notes (R14-R16): 128^2 tile, B-direct-from-L2, and
// 2-blocks/CU variants all regress; >=1 A-reg-set live across MFMA spills.
#define BM 256
#define BN 256
#define BK 64
#define NGT 32            // 4 m-tiles x 8 k-tiles

__global__ __launch_bounds__(512, 1) void gemm_proj(
    const float*    __restrict__ xt,      // [MROWS][512] f32
    const _Float16* __restrict__ Wcat,    // [1024][512]  f16
    const float* __restrict__ bfv, const float* __restrict__ brv, const float* __restrict__ bcv,
    _Float16* __restrict__ xp_h, _Float16* __restrict__ f_h,
    _Float16* __restrict__ r_h,  _Float16* __restrict__ cx_h)
{
    __shared__ char lds[131072];   // A: [parity][half][128 rows][128B]; B: +65536

    const int tid  = threadIdx.x;
    const int lane = tid & 63;
    const int w    = tid >> 6;       // 0..7
    const int wrq  = w >> 2;         // 0..1
    const int wcq  = w & 3;          // 0..3
    const int lr = lane & 15, lk = lane >> 4;

    // XCD-chunked bijective swizzle: 256 wgs, 32/XCD; the 4 cg-blocks of one
    // mgrp are co-XCD (A f32 panel read 4x -> 3 of 4 served by that XCD L2).
    int wg = (blockIdx.x & 7) * 32 + (blockIdx.x >> 3);
    const int  cg   = wg & 3;        // output group 0..3
    const int  mgrp = wg >> 2;       // 0..63
    const long m0 = (long)mgrp * 1024;   // 4 m-tiles of 256 rows
    const int  n0 = cg * BN;

    // ---- A staging maps (reg-staged f32, coalesced 16B/lane) ----
    const char* baseAg = (const char*)xt + (m0 + (tid >> 4)) * 2048 + (tid & 15) * 16;
    const int awbase = (tid >> 4) * 128 + (((tid & 15) * 8) ^ (((tid >> 4) & 7) << 4));

    const int rl8  = lane >> 3;
    const int scol = (((lane & 7) ^ rl8) << 4);
    const char* baseB = (const char*)Wcat + ((long)(n0 + w * 8 + rl8)) * 1024 + scol;

    // single A reg set (static indexing only — rule 20)
    float4 av_h0[4], av_h1[4];
#define ALOAD_H(gi, half, dst) do {                                          \
        const char* _b = baseAg + (long)((gi) >> 3) * 524288                 \
                         + ((gi) & 7) * 256 + (half) * 262144;               \
        _Pragma("unroll")                                                    \
        for (int jj = 0; jj < 4; ++jj)                                       \
            dst[jj] = *(const float4*)(_b + jj * 65536);                     \
    } while (0)
#define AWRITE_H(gi, half, src) do {                                         \
        char* _d = lds + ((gi) & 1) * 32768 + (half) * 16384 + awbase;       \
        _Pragma("unroll")                                                    \
        for (int jj = 0; jj < 4; ++jj) {                                     \
            f16x4 _h;                                                        \
            _h[0] = (_Float16)src[jj].x; _h[1] = (_Float16)src[jj].y;        \
            _h[2] = (_Float16)src[jj].z; _h[3] = (_Float16)src[jj].w;        \
            *(f16x4*)(_d + jj * 4096) = _h;                                  \
        }                                                                    \
    } while (0)
#define STAGE_B(g, h) do {                                                   \
        char* _d = lds + 65536 + ((g) & 1) * 32768 + (h) * 16384 + w * 1024; \
        const char* _s = baseB + ((g) & 7) * 128 + (long)(h) * 131072;       \
        __builtin_amdgcn_global_load_lds(GLBP(_s),         LDSP(_d),        16, 0, 0); \
        __builtin_amdgcn_global_load_lds(GLBP(_s + 65536), LDSP(_d + 8192), 16, 0, 0); \
    } while (0)

    fx4 acc[2][2][4][2];
    #pragma unroll
    for (int a = 0; a < 2; ++a)
        #pragma unroll
        for (int b = 0; b < 2; ++b)
            #pragma unroll
            for (int c = 0; c < 4; ++c)
                #pragma unroll
                for (int d = 0; d < 2; ++d)
                    acc[a][b][c][d] = (fx4){0.f, 0.f, 0.f, 0.f};

    f16x8 Ar[4][2];    // current A-half fragments [mf][kk]
    f16x8 B0r[2][2];   // B-half0 fragments [nf][kk]
    f16x8 B1r[2][2];   // B-half1 fragments

#define READ_A(c2, h) do {                                                   \
        _Pragma("unroll")                                                    \
        for (int mf = 0; mf < 4; ++mf) {                                     \
            int rl = wrq * 64 + mf * 16 + lr;                                \
            int rb = (c2) * 32768 + (h) * 16384 + rl * 128;                  \
            _Pragma("unroll")                                                \
            for (int kk = 0; kk < 2; ++kk)                                   \
                Ar[mf][kk] = *(const f16x8*)(lds + rb +                      \
                    ((kk * 64 + lk * 16) ^ ((rl & 7) << 4)));                \
        }                                                                    \
    } while (0)
#define READ_B(c2, h, dst) do {                                              \
        _Pragma("unroll")                                                    \
        for (int nf = 0; nf < 2; ++nf) {                                     \
            int rl = wcq * 32 + nf * 16 + lr;                                \
            int rb = 65536 + (c2) * 32768 + (h) * 16384 + rl * 128;          \
            _Pragma("unroll")                                                \
            for (int kk = 0; kk < 2; ++kk)                                   \
                dst[nf][kk] = *(const f16x8*)(lds + rb +                     \
                    ((kk * 64 + lk * 16) ^ ((rl & 7) << 4)));                \
        }                                                                    \
    } while (0)
    // swapped operands: D[col=lane&15 -> m (A)], [reg j -> o (B)]
#define MMACC(Qr, Qc, Br) do {                                               \
        __builtin_amdgcn_s_setprio(1);                                       \
        _Pragma("unroll")                                                    \
        for (int kk = 0; kk < 2; ++kk)                                       \
            _Pragma("unroll")                                                \
            for (int mf = 0; mf < 4; ++mf)                                   \
                _Pragma("unroll")                                            \
                for (int nf = 0; nf < 2; ++nf)                               \
                    acc[Qr][Qc][mf][nf] = __builtin_amdgcn_mfma_f32_16x16x32_f16( \
                        Br[nf][kk], Ar[mf][kk], acc[Qr][Qc][mf][nf], 0, 0, 0);    \
        __builtin_amdgcn_s_setprio(0);                                       \
    } while (0)

    const int g_out = cg;
    _Float16* outp = (g_out == 0) ? xp_h : (g_out == 1) ? f_h : (g_out == 2) ? r_h : cx_h;
    const float* bias = (g_out == 1) ? bfv : (g_out == 2) ? brv : (g_out == 3) ? bcv : nullptr;

    // ---- prologue: A(0)->LDS; B(0,*)->LDS; A(1) left in flight ----
    ALOAD_H(0, 0, av_h0); ALOAD_H(0, 1, av_h1);    // 8 vm
    STAGE_B(0, 0); STAGE_B(0, 1);                  // +4 = 12
    WAITVM(4);                                     // A(0,*) landed
    AWRITE_H(0, 0, av_h0); AWRITE_H(0, 1, av_h1);
    ALOAD_H(1, 0, av_h0); ALOAD_H(1, 1, av_h1);    // +8 = 12
    WAITVM(8);                                     // B(0,*) landed; leaves A(1)x8
    WAITLGKM0();                                   // A writes visible
    BAR();

    for (int g = 0; g < NGT; ++g) {
        const int c2 = g & 1;
        // ---- phase 1: Q(0,0) ----
        READ_A(c2, 0);
        READ_B(c2, 0, B0r);
        if (g + 1 < NGT) STAGE_B(g + 1, 0);        // opposite parity: safe
        WAITLGKM0();
        MMACC(0, 0, B0r);
        // ---- phase 2: Q(0,1) ----
        READ_B(c2, 1, B1r);
        if (g + 1 < NGT) STAGE_B(g + 1, 1);
        WAITLGKM0();
        MMACC(0, 1, B1r);
        // ---- phase 3: Q(1,0) ----  (no barrier, no vm gate)
        READ_A(c2, 1);
        WAITLGKM0();
        MMACC(1, 0, B0r);
        // ---- phase 4: Q(1,1) + drain + A publish + next-next A issue ----
        MMACC(1, 1, B1r);
        WAITVM(0);                       // A(g+1) full-tile old; B(g+1,*) L2-hot
        if (g + 1 < NGT) {
            AWRITE_H(g + 1, 0, av_h0);   // set now dead ->
            AWRITE_H(g + 1, 1, av_h1);
            if (g + 2 < NGT) {           // reload immediately
                ALOAD_H(g + 2, 0, av_h0);
                ALOAD_H(g + 2, 1, av_h1);
            }
        }
        WAITLGKM0();                     // A ds_writes + reads complete
        BAR();                           // single tile-boundary barrier
        // ---- per-m-tile epilogue (g = mt*8+7): packed f16x4 stores ----
        if ((g & 7) == 7) {
            const long mbase = m0 + (long)(g >> 3) * 256;
            #pragma unroll
            for (int Qr = 0; Qr < 2; ++Qr) {
                #pragma unroll
                for (int Qc = 0; Qc < 2; ++Qc) {
                    #pragma unroll
                    for (int nf = 0; nf < 2; ++nf) {
                        const int ob = Qc * 128 + wcq * 32 + nf * 16 + lk * 4;
                        float4 bv4 = (g_out == 0) ? (float4){0.f, 0.f, 0.f, 0.f}
                                                  : *(const float4*)(bias + ob);
                        #pragma unroll
                        for (int mf = 0; mf < 4; ++mf) {
                            long row = mbase + Qr * 128 + wrq * 64 + mf * 16 + lr;
                            fx4 v = acc[Qr][Qc][mf][nf];
                            f16x4 hv;
                            if (g_out == 1 || g_out == 2) {
                                float p0 = v[0] + bv4.x, p1 = v[1] + bv4.y;
                                float p2 = v[2] + bv4.z, p3 = v[3] + bv4.w;
                                hv[0] = (_Float16)(__builtin_amdgcn_rcpf(1.0f + __expf(-p0)));
                                hv[1] = (_Float16)(__builtin_amdgcn_rcpf(1.0f + __expf(-p1)));
                                hv[2] = (_Float16)(__builtin_amdgcn_rcpf(1.0f + __expf(-p2)));
                                hv[3] = (_Float16)(__builtin_amdgcn_rcpf(1.0f + __expf(-p3)));
                            } else {
                                hv[0] = (_Float16)(v[0] + bv4.x);
                                hv[1] = (_Float16)(v[1] + bv4.y);
                                hv[2] = (_Float16)(v[2] + bv4.z);
                                hv[3] = (_Float16)(v[3] + bv4.w);
                            }
                            *(f16x4*)(outp + row * NOUT + ob) = hv;
                            acc[Qr][Qc][mf][nf] = (fx4){0.f, 0.f, 0.f, 0.f};
                        }
                    }
                }
            }
        }
    }
}

// ---------------- pass 2a: per-chunk affine composition (f16x4 loads) -----
__global__ __launch_bounds__(256) void chunk_scan_a(
    const _Float16* __restrict__ f_h, const _Float16* __restrict__ xp_h,
    float* __restrict__ chunkA, float* __restrict__ chunkB)
{
    int tid2 = blockIdx.x * 256 + threadIdx.x;   // 65536 threads
    int ch = tid2 >> 11;
    int b4 = (tid2 & 2047) << 2;                 // 4 consecutive bo lanes
    long base = (long)ch * CHLEN * BO + b4;
    fx4 a = (fx4){1.f, 1.f, 1.f, 1.f};
    fx4 cc = (fx4){0.f, 0.f, 0.f, 0.f};
    for (int s = 0; s < CHLEN; ++s) {
        long i = base + (long)s * BO;
        f16x4 fv = *(const f16x4*)(f_h + i);
        f16x4 xv = *(const f16x4*)(xp_h + i);
        #pragma unroll
        for (int q = 0; q < 4; ++q) {
            float f = (float)fv[q], x = (float)xv[q];
            cc[q] = f * cc[q] + (1.f - f) * x;
            a[q] *= f;
        }
    }
    *(fx4*)(chunkA + ch * BO + b4) = a;
    *(fx4*)(chunkB + ch * BO + b4) = cc;
}

// ---------------- pass 2b: propagate chunk states ----
__global__ __launch_bounds__(256) void chunk_prop(
    const float* __restrict__ ct0,
    const float* __restrict__ chunkA, const float* __restrict__ chunkB,
    float* __restrict__ cin, float* __restrict__ c_final)
{
    int bo = blockIdx.x * 256 + threadIdx.x;   // 8192
    float c = ct0[bo];
    #pragma unroll
    for (int ch = 0; ch < NCHUNK; ++ch) {
        cin[ch * BO + bo] = c;
        c = chunkA[ch * BO + bo] * c + chunkB[ch * BO + bo];
    }
    c_final[bo] = c;
}

// ---------------- pass 2c: final scan producing ht (f16x4/float4) --------
__global__ __launch_bounds__(256) void chunk_scan_h(
    const _Float16* __restrict__ xp_h, const _Float16* __restrict__ f_h,
    const _Float16* __restrict__ r_h,  const _Float16* __restrict__ cx_h,
    const float* __restrict__ cin, float* __restrict__ ht)
{
    int tid2 = blockIdx.x * 256 + threadIdx.x;   // 65536 threads
    int ch = tid2 >> 11;
    int b4 = (tid2 & 2047) << 2;
    long base = (long)ch * CHLEN * BO + b4;
    fx4 c = *(const fx4*)(cin + ch * BO + b4);
    for (int s = 0; s < CHLEN; ++s) {
        long i = base + (long)s * BO;
        f16x4 fv  = *(const f16x4*)(f_h + i);
        f16x4 xv  = *(const f16x4*)(xp_h + i);
        f16x4 rv  = *(const f16x4*)(r_h + i);
        f16x4 cxv = *(const f16x4*)(cx_h + i);
        fx4 h4;
        #pragma unroll
        for (int q = 0; q < 4; ++q) {
            float f = (float)fv[q], x = (float)xv[q];
            float r = (float)rv[q], cx = (float)cxv[q];
            c[q] = f * c[q] + (1.f - f) * x;
            float e = __expf(2.f * c[q]);                  // tanh=(e-1)/(e+1)
            float th = (e - 1.f) * __builtin_amdgcn_rcpf(e + 1.f);
            h4[q] = r * th + (1.f - r) * cx;
        }
        *(fx4*)(ht + i) = h4;
    }
}

// ---------------- launcher ----------------
extern "C" void kernel_launch(void* const* d_in, const int* in_sizes, int n_in,
                              void* d_out, int out_size, void* d_ws, size_t ws_size,
                              hipStream_t stream) {
    const float* xt  = (const float*)d_in[0];
    const float* ct0 = (const float*)d_in[1];
    const float* Wx  = (const float*)d_in[2];
    const float* Wf  = (const float*)d_in[3];
    const float* bf_ = (const float*)d_in[4];
    const float* Wr  = (const float*)d_in[5];
    const float* br_ = (const float*)d_in[6];
    const float* Wc  = (const float*)d_in[7];
    const float* bc_ = (const float*)d_in[8];

    float* ht      = (float*)d_out;
    float* c_final = ht + (size_t)MROWS * NOUT;

    char* ws = (char*)d_ws;
    _Float16* Wcat = (_Float16*)ws;                          // 1 MiB
    _Float16* xp_h = (_Float16*)(ws + (1 << 20));            // 32 MiB each
    _Float16* f_h  = xp_h + (size_t)MROWS * NOUT;
    _Float16* r_h  = f_h  + (size_t)MROWS * NOUT;
    _Float16* cx_h = r_h  + (size_t)MROWS * NOUT;
    float* chunkA  = (float*)(cx_h + (size_t)MROWS * NOUT);  // 1 MiB
    float* chunkB  = chunkA + NCHUNK * BO;
    float* cin     = chunkB + NCHUNK * BO;
    // total ws use ~ 132 MiB

    convert_w<<<512, 256, 0, stream>>>(Wx, Wf, Wr, Wc, Wcat);
    gemm_proj<<<256, 512, 0, stream>>>(
        xt, Wcat, bf_, br_, bc_, xp_h, f_h, r_h, cx_h);
    chunk_scan_a<<<256, 256, 0, stream>>>(f_h, xp_h, chunkA, chunkB);
    chunk_prop<<<BO / 256, 256, 0, stream>>>(ct0, chunkA, chunkB, cin, c_final);
    chunk_scan_h<<<256, 256, 0, stream>>>(xp_h, f_h, r_h, cx_h, cin, ht);
}